// Round 1
// baseline (40690.878 us; speedup 1.0000x reference)
//
#include <hip/hip_runtime.h>
#include <cstdint>
#include <cstddef>

#define BATCH 128
#define SEQT  512
#define EMB_D 300
#define NU0   256
#define NU1   512
#define NU2   256
#define NDENSE 64

// ---------------------------------------------------------------------------
// Generic fp32 tiled GEMM: out[M,N] = A[M,K] @ W[K,N] + bias[N]
// A rows come either from a dense matrix A, or (tokens!=nullptr) gathered
// embedding rows: row m -> emb[tokens[b*SEQT + t0 + tl]] with m = b*CH + tl.
// BM=BN=64, BK=16, 256 threads, 4x4 micro-tile per thread.
// ---------------------------------------------------------------------------
__global__ __launch_bounds__(256) void gemm_xg(
    const float* __restrict__ A,
    const int*   __restrict__ tokens,
    const float* __restrict__ emb,
    int t0, int CH_log2,
    const float* __restrict__ W,
    const float* __restrict__ bias,
    float* __restrict__ out,
    int M, int N, int K)
{
    __shared__ __align__(16) float As[16][68];   // [k][m], padded row (272B, 16B-mult)
    __shared__ __align__(16) float Ws[16][64];   // [k][n]

    const int tid = threadIdx.x;
    const int m0 = blockIdx.x * 64;
    const int n0 = blockIdx.y * 64;

    const int lk  = tid & 15;   // A-load: k within tile
    const int lm  = tid >> 4;   // A-load: row group
    const int ln  = tid & 63;   // W-load: n
    const int lkk = tid >> 6;   // W-load: k group
    const int mt  = tid >> 4;   // compute: row block 0..15
    const int nt  = tid & 15;   // compute: col block 0..15

    float acc[4][4] = {};

    for (int k0 = 0; k0 < K; k0 += 16) {
        // ---- stage A tile (64 rows x 16 k) ----
        #pragma unroll
        for (int r = 0; r < 4; ++r) {
            const int ml = lm + r * 16;
            const int m  = m0 + ml;
            const float* src;
            if (tokens) {
                const int b  = m >> CH_log2;
                const int tl = m & ((1 << CH_log2) - 1);
                const int tok = tokens[b * SEQT + t0 + tl];
                src = emb + (size_t)tok * EMB_D;
            } else {
                src = A + (size_t)m * K;
            }
            const int k = k0 + lk;
            As[lk][ml] = (k < K) ? src[k] : 0.f;
        }
        // ---- stage W tile (16 k x 64 n) ----
        #pragma unroll
        for (int r = 0; r < 4; ++r) {
            const int kk = lkk + r * 4;
            const int k  = k0 + kk;
            Ws[kk][ln] = (k < K) ? W[(size_t)k * N + n0 + ln] : 0.f;
        }
        __syncthreads();

        #pragma unroll
        for (int kk = 0; kk < 16; ++kk) {
            const float4 a4 = *reinterpret_cast<const float4*>(&As[kk][mt * 4]);
            const float4 b4 = *reinterpret_cast<const float4*>(&Ws[kk][nt * 4]);
            const float av[4] = {a4.x, a4.y, a4.z, a4.w};
            const float bv[4] = {b4.x, b4.y, b4.z, b4.w};
            #pragma unroll
            for (int i = 0; i < 4; ++i)
                #pragma unroll
                for (int j = 0; j < 4; ++j)
                    acc[i][j] += av[i] * bv[j];
        }
        __syncthreads();
    }

    // ---- epilogue: +bias, store ----
    #pragma unroll
    for (int i = 0; i < 4; ++i) {
        const int m = m0 + mt * 4 + i;
        float* op = out + (size_t)m * N + n0 + nt * 4;
        float4 o4;
        o4.x = acc[i][0] + bias[n0 + nt * 4 + 0];
        o4.y = acc[i][1] + bias[n0 + nt * 4 + 1];
        o4.z = acc[i][2] + bias[n0 + nt * 4 + 2];
        o4.w = acc[i][3] + bias[n0 + nt * 4 + 3];
        *reinterpret_cast<float4*>(op) = o4;
    }
}

// ---------------------------------------------------------------------------
// One LSTM time step: for all (b, j):
//   g = xg[b, t, :] + h_prev[b, :] @ U         (4 gate columns per thread)
//   i,f,o = sigmoid; cand = relu(g_c); c = f*c + i*cand; h = o*relu(c)
// Workgroup = 8 batch rows x 32 columns (256 threads). h rows staged in LDS.
// c updated in place (only owner thread touches c[b,j]); h ping-pongs.
// ---------------------------------------------------------------------------
__global__ __launch_bounds__(256) void lstm_step(
    const float* __restrict__ xg_t,    // xg + tl*4u ; per-b stride = CH*4u
    const float* __restrict__ U,       // [u, 4u] row-major, gates i,f,c,o
    const float* __restrict__ h_in,    // [B, u]
    float* __restrict__ h_out,         // [B, u]
    float* __restrict__ c_state,       // [B, u] (in-place)
    float* __restrict__ hseq_t,        // hseq + tl*u or nullptr; per-b stride = CH*u
    int u, int u_log2, int CH)
{
    __shared__ float hs[8 * 512];

    const int tid = threadIdx.x;
    const int jl = tid & 31;
    const int bl = tid >> 5;            // 0..7
    const int bbase = blockIdx.x * 8;
    const int j = blockIdx.y * 32 + jl;

    // stage 8 rows of h_prev
    for (int idx = tid; idx < 8 * u; idx += 256) {
        const int r   = idx >> u_log2;
        const int col = idx & (u - 1);
        hs[idx] = h_in[(size_t)(bbase + r) * u + col];
    }
    __syncthreads();

    const int fu = 4 * u;
    const float* Ub = U + j;
    const float* hr = hs + bl * u;

    float ai = 0.f, af = 0.f, ac = 0.f, ao = 0.f;
    #pragma unroll 4
    for (int k = 0; k < u; ++k) {
        const float hk = hr[k];
        const float* up = Ub + (size_t)k * fu;
        ai += hk * up[0];
        af += hk * up[u];
        ac += hk * up[2 * u];
        ao += hk * up[3 * u];
    }

    const int b = bbase + bl;
    const size_t xoff = (size_t)b * CH * fu + j;
    const float gi = xg_t[xoff]          + ai;
    const float gf = xg_t[xoff + u]      + af;
    const float gc = xg_t[xoff + 2 * u]  + ac;
    const float go = xg_t[xoff + 3 * u]  + ao;

    const float i_ = 1.f / (1.f + __expf(-gi));
    const float f_ = 1.f / (1.f + __expf(-gf));
    const float o_ = 1.f / (1.f + __expf(-go));
    const float cand = fmaxf(gc, 0.f);

    const size_t so = (size_t)b * u + j;
    const float cn = f_ * c_state[so] + i_ * cand;
    c_state[so] = cn;
    const float hn = o_ * fmaxf(cn, 0.f);
    h_out[so] = hn;
    if (hseq_t) hseq_t[(size_t)b * CH * u + j] = hn;
}

// ---------------------------------------------------------------------------
// Head: out[b] = sigmoid( relu(h2[b,:] @ Wd + bd) @ Wc + bc )
// One block (64 threads = 1 wave) per batch row.
// ---------------------------------------------------------------------------
__global__ __launch_bounds__(64) void head_kernel(
    const float* __restrict__ h2,   // [B, 256]
    const float* __restrict__ Wd,   // [256, 64]
    const float* __restrict__ bd,   // [64]
    const float* __restrict__ Wc,   // [64, 1]
    const float* __restrict__ bc,   // [1]
    float* __restrict__ out)        // [B]
{
    const int b = blockIdx.x;
    const int j = threadIdx.x;      // 0..63
    float a = bd[j];
    const float* hrow = h2 + (size_t)b * NU2;
    #pragma unroll 4
    for (int k = 0; k < NU2; ++k)
        a += hrow[k] * Wd[(size_t)k * NDENSE + j];
    a = fmaxf(a, 0.f) * Wc[j];
    #pragma unroll
    for (int off = 32; off > 0; off >>= 1)
        a += __shfl_down(a, off);
    if (j == 0)
        out[b] = 1.f / (1.f + expf(-(a + bc[0])));
}

// ---------------------------------------------------------------------------
extern "C" void kernel_launch(void* const* d_in, const int* in_sizes, int n_in,
                              void* d_out, int out_size, void* d_ws, size_t ws_size,
                              hipStream_t stream)
{
    const int*   tokens = (const int*)  d_in[0];
    const float* emb    = (const float*)d_in[1];
    const float* W0     = (const float*)d_in[2];
    const float* Ur0    = (const float*)d_in[3];
    const float* b0     = (const float*)d_in[4];
    const float* W1     = (const float*)d_in[5];
    const float* Ur1    = (const float*)d_in[6];
    const float* b1     = (const float*)d_in[7];
    const float* W2     = (const float*)d_in[8];
    const float* Ur2    = (const float*)d_in[9];
    const float* b2     = (const float*)d_in[10];
    const float* Wd     = (const float*)d_in[11];
    const float* bd     = (const float*)d_in[12];
    const float* Wc     = (const float*)d_in[13];
    const float* bc     = (const float*)d_in[14];
    float* out = (float*)d_out;

    // choose time-chunk CH (power of two) to fit workspace
    int CH = 128, CHL = 7;
    auto need = [](int ch) -> size_t {
        return (size_t)4 * BATCH * ch * (2048 + 256 + 512) + (size_t)(1 << 22);
    };
    while (CH > 1 && need(CH) > ws_size) { CH >>= 1; CHL--; }

    char* p = (char*)d_ws;
    float* xg  = (float*)p;  p += (size_t)4 * BATCH * CH * 2048;  // gate scratch (max 4u)
    float* hs0 = (float*)p;  p += (size_t)4 * BATCH * CH * 256;   // layer0 h-seq chunk
    float* hs1 = (float*)p;  p += (size_t)4 * BATCH * CH * 512;   // layer1 h-seq chunk
    float* st  = (float*)p;                                        // states
    float* h0a = st;              float* h0b = h0a + BATCH * NU0;  float* c0 = h0b + BATCH * NU0;
    float* h1a = c0 + BATCH*NU0;  float* h1b = h1a + BATCH * NU1;  float* c1 = h1b + BATCH * NU1;
    float* h2a = c1 + BATCH*NU1;  float* h2b = h2a + BATCH * NU2;  float* c2 = h2b + BATCH * NU2;
    const size_t st_bytes = (size_t)4 * (3 * BATCH * NU0 + 3 * BATCH * NU1 + 3 * BATCH * NU2);
    hipMemsetAsync(st, 0, st_bytes, stream);

    const int nc = SEQT / CH;
    for (int c = 0; c < nc; ++c) {
        const int t0 = c * CH;

        // ---- layer 0: xg = emb[tokens] @ W0 + b0 ----
        {
            dim3 g(BATCH * CH / 64, (4 * NU0) / 64);
            gemm_xg<<<g, 256, 0, stream>>>(nullptr, tokens, emb, t0, CHL,
                                           W0, b0, xg, BATCH * CH, 4 * NU0, EMB_D);
        }
        for (int tl = 0; tl < CH; ++tl) {
            const int t = t0 + tl;
            float* hin  = (t & 1) ? h0b : h0a;
            float* hout = (t & 1) ? h0a : h0b;
            dim3 g(BATCH / 8, NU0 / 32);
            lstm_step<<<g, 256, 0, stream>>>(xg + (size_t)tl * 4 * NU0, Ur0, hin, hout, c0,
                                             hs0 + (size_t)tl * NU0, NU0, 8, CH);
        }
        // ---- layer 1: xg = hs0 @ W1 + b1 ----
        {
            dim3 g(BATCH * CH / 64, (4 * NU1) / 64);
            gemm_xg<<<g, 256, 0, stream>>>(hs0, nullptr, nullptr, 0, 0,
                                           W1, b1, xg, BATCH * CH, 4 * NU1, NU0);
        }
        for (int tl = 0; tl < CH; ++tl) {
            const int t = t0 + tl;
            float* hin  = (t & 1) ? h1b : h1a;
            float* hout = (t & 1) ? h1a : h1b;
            dim3 g(BATCH / 8, NU1 / 32);
            lstm_step<<<g, 256, 0, stream>>>(xg + (size_t)tl * 4 * NU1, Ur1, hin, hout, c1,
                                             hs1 + (size_t)tl * NU1, NU1, 9, CH);
        }
        // ---- layer 2: xg = hs1 @ W2 + b2 ----
        {
            dim3 g(BATCH * CH / 64, (4 * NU2) / 64);
            gemm_xg<<<g, 256, 0, stream>>>(hs1, nullptr, nullptr, 0, 0,
                                           W2, b2, xg, BATCH * CH, 4 * NU2, NU1);
        }
        for (int tl = 0; tl < CH; ++tl) {
            const int t = t0 + tl;
            float* hin  = (t & 1) ? h2b : h2a;
            float* hout = (t & 1) ? h2a : h2b;
            dim3 g(BATCH / 8, NU2 / 32);
            lstm_step<<<g, 256, 0, stream>>>(xg + (size_t)tl * 4 * NU2, Ur2, hin, hout, c2,
                                             nullptr, NU2, 8, CH);
        }
    }

    // final h of layer 2 was written at t=511 -> h2a
    head_kernel<<<BATCH, 64, 0, stream>>>(h2a, Wd, bd, Wc, bc, out);
}